// Round 5
// baseline (218.251 us; speedup 1.0000x reference)
//
#include <hip/hip_runtime.h>

// B=8, T=2048, C=1024, H=64.  Reference: softmax over QUERY axis (dim=1),
// no 1/sqrt(d) scale.  out[t,h] = sum_{s<=t} exp(q_t.k_s)/D_s * v[s,h],
// D_s = sum_{t>=s} exp(q_t.k_s).
// Split-bf16 (hi+lo, 3-term) MFMA for qkv GEMM and QK dots; plain bf16 V / P.

typedef __attribute__((ext_vector_type(8))) short bf16x8;
typedef __attribute__((ext_vector_type(4))) float f32x4;
typedef unsigned short u16;

#define MFMA(a, b, c) __builtin_amdgcn_mfma_f32_16x16x32_bf16((a), (b), (c), 0, 0, 0)

__device__ __forceinline__ u16 f2bf(float x) {           // RNE fp32 -> bf16
    unsigned u = __float_as_uint(x);
    u += 0x7fff + ((u >> 16) & 1);
    return (u16)(u >> 16);
}
__device__ __forceinline__ float bf2f(u16 h) {
    return __uint_as_float(((unsigned)h) << 16);
}

// ws byte offsets
#define WH_OFF 0u
#define WL_OFF (WH_OFF + 192u*1024u*2u)
#define QH_OFF (WL_OFF + 192u*1024u*2u)
#define QL_OFF (QH_OFF + 8u*2048u*64u*2u)
#define KH_OFF (QL_OFF + 8u*2048u*64u*2u)
#define KL_OFF (KH_OFF + 8u*2048u*64u*2u)
#define VT_OFF (KL_OFF + 8u*2048u*64u*2u)
#define DD_OFF (VT_OFF + 8u*2048u*64u*2u)   // fp32 [B][T]

// ---------------------------------------------------------------------------
// W pre-split: rows 0..63 = Wq, 64..127 = Wk, 128..191 = Wv
// ---------------------------------------------------------------------------
__global__ __launch_bounds__(256) void wsplit_kernel(
    const float* __restrict__ Wk, const float* __restrict__ Wq,
    const float* __restrict__ Wv, u16* __restrict__ WH, u16* __restrict__ WL)
{
    const int n = blockIdx.x;
    const float* src = (n < 64) ? (Wq + (long)n * 1024)
                     : (n < 128) ? (Wk + (long)(n - 64) * 1024)
                                 : (Wv + (long)(n - 128) * 1024);
    const float4 f = ((const float4*)src)[threadIdx.x];
    const float v[4] = {f.x, f.y, f.z, f.w};
    u16 hi[4], lo[4];
    #pragma unroll
    for (int j = 0; j < 4; ++j) {
        hi[j] = f2bf(v[j]);
        lo[j] = f2bf(v[j] - bf2f(hi[j]));
    }
    *(ushort4*)&WH[(long)n * 1024 + 4 * threadIdx.x] = make_ushort4(hi[0], hi[1], hi[2], hi[3]);
    *(ushort4*)&WL[(long)n * 1024 + 4 * threadIdx.x] = make_ushort4(lo[0], lo[1], lo[2], lo[3]);
}

// ---------------------------------------------------------------------------
// qkv: [16384x1024] @ [1024x192].  M-tile 64, 512 thr (8 waves: 2m x 4n,
// per-wave 32x48), K-step 64, LDS double-buffered + register prefetch.
// Row layout: [hi 64 | lo 64 | pad 8] u16 = 272B rows (16B-aligned).
// Grid 256 = 1 block/CU.
// ---------------------------------------------------------------------------
__global__ __launch_bounds__(512) void qkv_kernel(
    const float* __restrict__ idx, const u16* __restrict__ WH, const u16* __restrict__ WL,
    u16* __restrict__ QH, u16* __restrict__ QL,
    u16* __restrict__ KH, u16* __restrict__ KL, u16* __restrict__ VT)
{
    __shared__ u16 a_l[2][64 * 136];
    __shared__ u16 w_l[2][192 * 136];
    const int tid = threadIdx.x;
    const int w = tid >> 6, lr = tid & 15, quad = (tid >> 4) & 3;
    const int r0 = blockIdx.x * 64;
    const int b = r0 >> 11, t0 = r0 & 2047;
    const int m0 = (w & 1) * 32;
    const int nb = (w >> 1) * 48;

    f32x4 acc[2][3] = {};
    float4 pa[2], pwh[3], pwl[3];

    // ---- prologue: load + stage c0 = 0 into buffer 0
    #pragma unroll
    for (int i2 = 0; i2 < 2; ++i2) {
        const int e = i2 * 512 + tid, r = e >> 4, c4 = e & 15;
        pa[i2] = *(const float4*)&idx[(long)(r0 + r) * 1024 + 4 * c4];
    }
    #pragma unroll
    for (int i2 = 0; i2 < 3; ++i2) {
        const int e = i2 * 512 + tid, n = e >> 3, c8 = e & 7;
        pwh[i2] = *(const float4*)&WH[(long)n * 1024 + 8 * c8];
        pwl[i2] = *(const float4*)&WL[(long)n * 1024 + 8 * c8];
    }
    #pragma unroll
    for (int i2 = 0; i2 < 2; ++i2) {
        const int e = i2 * 512 + tid, r = e >> 4, c4 = e & 15;
        const float v[4] = {pa[i2].x, pa[i2].y, pa[i2].z, pa[i2].w};
        u16 hi[4], lo[4];
        #pragma unroll
        for (int j = 0; j < 4; ++j) { hi[j] = f2bf(v[j]); lo[j] = f2bf(v[j] - bf2f(hi[j])); }
        *(ushort4*)&a_l[0][r * 136 + 4 * c4]      = make_ushort4(hi[0], hi[1], hi[2], hi[3]);
        *(ushort4*)&a_l[0][r * 136 + 64 + 4 * c4] = make_ushort4(lo[0], lo[1], lo[2], lo[3]);
    }
    #pragma unroll
    for (int i2 = 0; i2 < 3; ++i2) {
        const int e = i2 * 512 + tid, n = e >> 3, c8 = e & 7;
        *(float4*)&w_l[0][n * 136 + 8 * c8]      = pwh[i2];
        *(float4*)&w_l[0][n * 136 + 64 + 8 * c8] = pwl[i2];
    }
    __syncthreads();

    int p = 0;
    for (int it = 0; it < 16; ++it) {
        // prefetch next K-chunk into registers (overlaps MFMA below)
        if (it < 15) {
            const int c0 = (it + 1) * 64;
            #pragma unroll
            for (int i2 = 0; i2 < 2; ++i2) {
                const int e = i2 * 512 + tid, r = e >> 4, c4 = e & 15;
                pa[i2] = *(const float4*)&idx[(long)(r0 + r) * 1024 + c0 + 4 * c4];
            }
            #pragma unroll
            for (int i2 = 0; i2 < 3; ++i2) {
                const int e = i2 * 512 + tid, n = e >> 3, c8 = e & 7;
                pwh[i2] = *(const float4*)&WH[(long)n * 1024 + c0 + 8 * c8];
                pwl[i2] = *(const float4*)&WL[(long)n * 1024 + c0 + 8 * c8];
            }
        }

        // hoist B frags once
        bf16x8 BH[3][2], BL[3][2];
        #pragma unroll
        for (int nf = 0; nf < 3; ++nf) {
            const int br = (nb + nf * 16 + lr) * 136 + quad * 8;
            #pragma unroll
            for (int kk = 0; kk < 2; ++kk) {
                BH[nf][kk] = *(const bf16x8*)&w_l[p][br + kk * 32];
                BL[nf][kk] = *(const bf16x8*)&w_l[p][br + 64 + kk * 32];
            }
        }
        #pragma unroll
        for (int mi = 0; mi < 2; ++mi) {
            const int ar = (m0 + mi * 16 + lr) * 136 + quad * 8;
            const bf16x8 ah0 = *(const bf16x8*)&a_l[p][ar];
            const bf16x8 ah1 = *(const bf16x8*)&a_l[p][ar + 32];
            const bf16x8 al0 = *(const bf16x8*)&a_l[p][ar + 64];
            const bf16x8 al1 = *(const bf16x8*)&a_l[p][ar + 96];
            #pragma unroll
            for (int nf = 0; nf < 3; ++nf) {
                f32x4 c = acc[mi][nf];
                c = MFMA(ah0, BH[nf][0], c);
                c = MFMA(al0, BH[nf][0], c);
                c = MFMA(ah0, BL[nf][0], c);
                c = MFMA(ah1, BH[nf][1], c);
                c = MFMA(al1, BH[nf][1], c);
                c = MFMA(ah1, BL[nf][1], c);
                acc[mi][nf] = c;
            }
        }

        if (it < 15) {
            #pragma unroll
            for (int i2 = 0; i2 < 2; ++i2) {
                const int e = i2 * 512 + tid, r = e >> 4, c4 = e & 15;
                const float v[4] = {pa[i2].x, pa[i2].y, pa[i2].z, pa[i2].w};
                u16 hi[4], lo[4];
                #pragma unroll
                for (int j = 0; j < 4; ++j) { hi[j] = f2bf(v[j]); lo[j] = f2bf(v[j] - bf2f(hi[j])); }
                *(ushort4*)&a_l[p ^ 1][r * 136 + 4 * c4]      = make_ushort4(hi[0], hi[1], hi[2], hi[3]);
                *(ushort4*)&a_l[p ^ 1][r * 136 + 64 + 4 * c4] = make_ushort4(lo[0], lo[1], lo[2], lo[3]);
            }
            #pragma unroll
            for (int i2 = 0; i2 < 3; ++i2) {
                const int e = i2 * 512 + tid, n = e >> 3, c8 = e & 7;
                *(float4*)&w_l[p ^ 1][n * 136 + 8 * c8]      = pwh[i2];
                *(float4*)&w_l[p ^ 1][n * 136 + 64 + 8 * c8] = pwl[i2];
            }
            __syncthreads();
            p ^= 1;
        }
    }

    // epilogue: C layout col = lane&15 (n), row = quad*4 + reg (m)
    #pragma unroll
    for (int mi = 0; mi < 2; ++mi) {
        const int tb = t0 + m0 + mi * 16 + quad * 4;
        #pragma unroll
        for (int nf = 0; nf < 3; ++nf) {
            const int n = nb + nf * 16 + lr;
            const f32x4 a = acc[mi][nf];
            if (n < 128) {
                u16* Hd = (n < 64) ? QH : KH;
                u16* Ld = (n < 64) ? QL : KL;
                const int h = n & 63;
                #pragma unroll
                for (int r = 0; r < 4; ++r) {
                    const float v = a[r];
                    const u16 hi = f2bf(v);
                    const u16 lo = f2bf(v - bf2f(hi));
                    const long o = (long)(b * 2048 + tb + r) * 64 + h;
                    Hd[o] = hi; Ld[o] = lo;
                }
            } else {
                *(ushort4*)&VT[(long)(b * 64 + n - 128) * 2048 + tb] =
                    make_ushort4(f2bf(a[0]), f2bf(a[1]), f2bf(a[2]), f2bf(a[3]));
            }
        }
    }
}

// ---------------------------------------------------------------------------
// stats: D_s = sum_{t>=s} exp(q_t.k_s).  K B-frags hoisted to registers for
// the whole t-loop; qt double-buffered + register prefetch (1 barrier/iter).
// Grid (80, B): s-tile i, t-chunk c; atomicAdd partials.
// ---------------------------------------------------------------------------
__global__ __launch_bounds__(256) void stats_kernel(
    const u16* __restrict__ QH, const u16* __restrict__ QL,
    const u16* __restrict__ KH, const u16* __restrict__ KL,
    float* __restrict__ D)
{
    __shared__ u16 kt[64 * 136];
    __shared__ u16 qt[2][64 * 136];
    __shared__ float red[4][64];
    const int tid = threadIdx.x;
    const int w = tid >> 6, lr = tid & 15, quad = (tid >> 4) & 3;
    const int b = blockIdx.y;
    int x = blockIdx.x, i = 0;
    for (;;) { const int nc = (39 - i) >> 3; if (x < nc) break; x -= nc; ++i; }
    const int c = x;
    const int s0 = i * 64;
    const int jt0 = i + 8 * c, jt1 = min(jt0 + 8, 32);

    // stage K tile + first q tile
    #pragma unroll
    for (int it = 0; it < 2; ++it) {
        const int e = it * 256 + tid, s = e >> 3, c8 = e & 7;
        const long g = (long)(b * 2048 + s0 + s) * 64 + 8 * c8;
        *(float4*)&kt[s * 136 + 8 * c8]      = *(const float4*)&KH[g];
        *(float4*)&kt[s * 136 + 64 + 8 * c8] = *(const float4*)&KL[g];
        const long gq = (long)(b * 2048 + jt0 * 64 + s) * 64 + 8 * c8;
        *(float4*)&qt[0][s * 136 + 8 * c8]      = *(const float4*)&QH[gq];
        *(float4*)&qt[0][s * 136 + 64 + 8 * c8] = *(const float4*)&QL[gq];
    }
    __syncthreads();

    // hoist K B-frags (fixed across t-loop)
    bf16x8 BH[4][2], BL[4][2];
    #pragma unroll
    for (int nf = 0; nf < 4; ++nf) {
        const int br = (nf * 16 + lr) * 136 + quad * 8;
        #pragma unroll
        for (int kk = 0; kk < 2; ++kk) {
            BH[nf][kk] = *(const bf16x8*)&kt[br + kk * 32];
            BL[nf][kk] = *(const bf16x8*)&kt[br + 64 + kk * 32];
        }
    }

    float dsum[4] = {0.f, 0.f, 0.f, 0.f};
    const int ar = (w * 16 + lr) * 136 + quad * 8;
    float4 fh[2], fl[2];
    int p = 0;
    for (int jt = jt0; jt < jt1; ++jt) {
        if (jt + 1 < jt1) {
            #pragma unroll
            for (int it = 0; it < 2; ++it) {
                const int e = it * 256 + tid, t = e >> 3, c8 = e & 7;
                const long g = (long)(b * 2048 + (jt + 1) * 64 + t) * 64 + 8 * c8;
                fh[it] = *(const float4*)&QH[g];
                fl[it] = *(const float4*)&QL[g];
            }
        }

        const bf16x8 ah0 = *(const bf16x8*)&qt[p][ar];
        const bf16x8 ah1 = *(const bf16x8*)&qt[p][ar + 32];
        const bf16x8 al0 = *(const bf16x8*)&qt[p][ar + 64];
        const bf16x8 al1 = *(const bf16x8*)&qt[p][ar + 96];
        #pragma unroll
        for (int nf = 0; nf < 4; ++nf) {
            f32x4 cc = {};
            cc = MFMA(ah0, BH[nf][0], cc);
            cc = MFMA(al0, BH[nf][0], cc);
            cc = MFMA(ah0, BL[nf][0], cc);
            cc = MFMA(ah1, BH[nf][1], cc);
            cc = MFMA(al1, BH[nf][1], cc);
            cc = MFMA(ah1, BL[nf][1], cc);

            if (jt > i) {
                dsum[nf] += __expf(cc[0]) + __expf(cc[1]) + __expf(cc[2]) + __expf(cc[3]);
            } else {   // diagonal tile: include t >= s only
                const int sl = nf * 16 + lr;
                #pragma unroll
                for (int r = 0; r < 4; ++r) {
                    const int tl = w * 16 + quad * 4 + r;
                    if (tl >= sl) dsum[nf] += __expf(cc[r]);
                }
            }
        }

        if (jt + 1 < jt1) {
            #pragma unroll
            for (int it = 0; it < 2; ++it) {
                const int e = it * 256 + tid, t = e >> 3, c8 = e & 7;
                *(float4*)&qt[p ^ 1][t * 136 + 8 * c8]      = fh[it];
                *(float4*)&qt[p ^ 1][t * 136 + 64 + 8 * c8] = fl[it];
            }
            __syncthreads();
            p ^= 1;
        }
    }

    #pragma unroll
    for (int nf = 0; nf < 4; ++nf) {
        dsum[nf] += __shfl_xor(dsum[nf], 16);
        dsum[nf] += __shfl_xor(dsum[nf], 32);
    }
    if (quad == 0) {
        #pragma unroll
        for (int nf = 0; nf < 4; ++nf) red[w][nf * 16 + lr] = dsum[nf];
    }
    __syncthreads();
    if (tid < 64)
        atomicAdd(&D[b * 2048 + s0 + tid],
                  red[0][tid] + red[1][tid] + red[2][tid] + red[3][tid]);
}

// ---------------------------------------------------------------------------
// out: q A-frags hoisted to regs (qt LDS then reused as wa, wave-private so
// barrier-free); kt/vt/rdt double-buffered + prefetch (1 barrier/iter).
// ---------------------------------------------------------------------------
__global__ __launch_bounds__(256) void out_kernel(
    const u16* __restrict__ QH, const u16* __restrict__ QL,
    const u16* __restrict__ KH, const u16* __restrict__ KL,
    const u16* __restrict__ VT, const float* __restrict__ D,
    float* __restrict__ out)
{
    __shared__ u16 qt_wa[64 * 136];   // q tile, then reused as wT (A-layout)
    __shared__ u16 kt[2][64 * 136];
    __shared__ u16 vt[2][64 * 72];
    __shared__ float rdt[2][64];
    const int tid = threadIdx.x;
    const int w = tid >> 6, lr = tid & 15, quad = (tid >> 4) & 3;
    const int b = blockIdx.y;
    int x = blockIdx.x, i = 0;
    for (;;) { const int nc = (i + 8) >> 3; if (x < nc) break; x -= nc; ++i; }
    const int c = x;
    const int t0 = i * 64;
    const int js0 = 8 * c, js1 = min(8 * c + 8, i + 1);

    // stage q tile + first k/v/rd
    #pragma unroll
    for (int it = 0; it < 2; ++it) {
        const int e = it * 256 + tid, t = e >> 3, c8 = e & 7;
        const long g = (long)(b * 2048 + t0 + t) * 64 + 8 * c8;
        *(float4*)&qt_wa[t * 136 + 8 * c8]      = *(const float4*)&QH[g];
        *(float4*)&qt_wa[t * 136 + 64 + 8 * c8] = *(const float4*)&QL[g];
        const long gk = (long)(b * 2048 + js0 * 64 + t) * 64 + 8 * c8;
        *(float4*)&kt[0][t * 136 + 8 * c8]      = *(const float4*)&KH[gk];
        *(float4*)&kt[0][t * 136 + 64 + 8 * c8] = *(const float4*)&KL[gk];
        *(float4*)&vt[0][t * 72 + 8 * c8] =
            *(const float4*)&VT[(long)(b * 64 + t) * 2048 + js0 * 64 + 8 * c8];
    }
    if (tid < 64) rdt[0][tid] = 1.0f / D[b * 2048 + js0 * 64 + tid];
    __syncthreads();

    // hoist q A-frags; qt_wa LDS is then dead -> becomes wa
    const int ar = (w * 16 + lr) * 136 + quad * 8;
    const bf16x8 qh0 = *(const bf16x8*)&qt_wa[ar];
    const bf16x8 qh1 = *(const bf16x8*)&qt_wa[ar + 32];
    const bf16x8 ql0 = *(const bf16x8*)&qt_wa[ar + 64];
    const bf16x8 ql1 = *(const bf16x8*)&qt_wa[ar + 96];

    f32x4 oacc[4] = {};
    float4 fkh[2], fkl[2], fv[2]; float fd;
    int p = 0;
    for (int js = js0; js < js1; ++js) {
        if (js + 1 < js1) {
            #pragma unroll
            for (int it = 0; it < 2; ++it) {
                const int e = it * 256 + tid, t = e >> 3, c8 = e & 7;
                const long gk = (long)(b * 2048 + (js + 1) * 64 + t) * 64 + 8 * c8;
                fkh[it] = *(const float4*)&KH[gk];
                fkl[it] = *(const float4*)&KL[gk];
                fv[it]  = *(const float4*)&VT[(long)(b * 64 + t) * 2048 + (js + 1) * 64 + 8 * c8];
            }
            if (tid < 64) fd = 1.0f / D[b * 2048 + (js + 1) * 64 + tid];
        }

        const bool diag = (js == i);
        #pragma unroll
        for (int nf = 0; nf < 4; ++nf) {
            const int br = (nf * 16 + lr) * 136 + quad * 8;
            f32x4 cc = {};
            const bf16x8 bh0 = *(const bf16x8*)&kt[p][br];
            const bf16x8 bl0 = *(const bf16x8*)&kt[p][br + 64];
            cc = MFMA(qh0, bh0, cc); cc = MFMA(ql0, bh0, cc); cc = MFMA(qh0, bl0, cc);
            const bf16x8 bh1 = *(const bf16x8*)&kt[p][br + 32];
            const bf16x8 bl1 = *(const bf16x8*)&kt[p][br + 96];
            cc = MFMA(qh1, bh1, cc); cc = MFMA(ql1, bh1, cc); cc = MFMA(qh1, bl1, cc);

            const int sl = nf * 16 + lr;
            const float rv = rdt[p][sl];
            #pragma unroll
            for (int r = 0; r < 4; ++r) {
                const int tl = w * 16 + quad * 4 + r;
                float wgt = __expf(cc[r]) * rv;
                if (diag && tl < sl) wgt = 0.f;
                qt_wa[tl * 136 + sl] = f2bf(wgt);    // own-wave strip only
            }
        }
        // PV: A = wa strip, B = vt [h][s]
        #pragma unroll
        for (int kk = 0; kk < 2; ++kk) {
            const bf16x8 av = *(const bf16x8*)&qt_wa[(w * 16 + lr) * 136 + kk * 32 + quad * 8];
            #pragma unroll
            for (int nf = 0; nf < 4; ++nf) {
                const bf16x8 bv = *(const bf16x8*)&vt[p][(nf * 16 + lr) * 72 + kk * 32 + quad * 8];
                oacc[nf] = MFMA(av, bv, oacc[nf]);
            }
        }

        if (js + 1 < js1) {
            #pragma unroll
            for (int it = 0; it < 2; ++it) {
                const int e = it * 256 + tid, t = e >> 3, c8 = e & 7;
                *(float4*)&kt[p ^ 1][t * 136 + 8 * c8]      = fkh[it];
                *(float4*)&kt[p ^ 1][t * 136 + 64 + 8 * c8] = fkl[it];
                *(float4*)&vt[p ^ 1][t * 72 + 8 * c8]       = fv[it];
            }
            if (tid < 64) rdt[p ^ 1][tid] = fd;
            __syncthreads();
            p ^= 1;
        }
    }

    const bool single = (i < 8);
    #pragma unroll
    for (int nf = 0; nf < 4; ++nf) {
        const int h = nf * 16 + lr;
        #pragma unroll
        for (int r = 0; r < 4; ++r) {
            const int t = t0 + w * 16 + quad * 4 + r;
            const long o = (long)(b * 2048 + t) * 64 + h;
            if (single) out[o] = oacc[nf][r];
            else        atomicAdd(&out[o], oacc[nf][r]);
        }
    }
}

extern "C" void kernel_launch(void* const* d_in, const int* in_sizes, int n_in,
                              void* d_out, int out_size, void* d_ws, size_t ws_size,
                              hipStream_t stream)
{
    const float* idx = (const float*)d_in[0];
    const float* Wk  = (const float*)d_in[1];
    const float* Wq  = (const float*)d_in[2];
    const float* Wv  = (const float*)d_in[3];
    char* ws = (char*)d_ws;
    float* out = (float*)d_out;

    u16* WH = (u16*)(ws + WH_OFF); u16* WL = (u16*)(ws + WL_OFF);
    u16* QH = (u16*)(ws + QH_OFF); u16* QL = (u16*)(ws + QL_OFF);
    u16* KH = (u16*)(ws + KH_OFF); u16* KL = (u16*)(ws + KL_OFF);
    u16* VT = (u16*)(ws + VT_OFF);
    float* Dp = (float*)(ws + DD_OFF);

    hipMemsetAsync(out, 0, (size_t)8 * 2048 * 64 * sizeof(float), stream);
    hipMemsetAsync(Dp, 0, (size_t)8 * 2048 * sizeof(float), stream);

    wsplit_kernel<<<192, 256, 0, stream>>>(Wk, Wq, Wv, WH, WL);
    qkv_kernel<<<256, 512, 0, stream>>>(idx, WH, WL, QH, QL, KH, KL, VT);
    stats_kernel<<<dim3(80, 8), 256, 0, stream>>>(QH, QL, KH, KL, Dp);
    out_kernel<<<dim3(80, 8), 256, 0, stream>>>(QH, QL, KH, KL, VT, Dp, out);
}